// Round 1
// baseline (3414.172 us; speedup 1.0000x reference)
//
#include <hip/hip_runtime.h>
#include <cstddef>

#define NWALKS 16384
#define TLEN   20
#define HDIM   128
#define WPB    32      // walks per block
#define XSTR   132     // LDS row stride in floats (bank-conflict-minimal, 16B aligned)

// ---------------------------------------------------------------------------
// fold: W_c = W_ih @ W_f  [384x128], b_c = W_ih @ b_f + b_ih  [384]
// gx[r] for a node is then  sum_i W_c[r][i] * x[node][i] + b_c[r]
// ---------------------------------------------------------------------------
__global__ void fold_kernel(const float* __restrict__ W_f, const float* __restrict__ b_f,
                            const float* __restrict__ W_ih, const float* __restrict__ b_ih,
                            float* __restrict__ W_c, float* __restrict__ b_c) {
  const int r = blockIdx.x;    // 0..383
  const int i = threadIdx.x;   // 0..127
  const float* wih = W_ih + r * HDIM;
  float acc = 0.f;
  for (int h = 0; h < HDIM; ++h)
    acc = fmaf(wih[h], W_f[h * HDIM + i], acc);
  W_c[r * HDIM + i] = acc;
  if (i == 0) {
    float bb = b_ih[r];
    for (int h = 0; h < HDIM; ++h) bb = fmaf(wih[h], b_f[h], bb);
    b_c[r] = bb;
  }
}

__device__ __forceinline__ float dot4(const float4 a, const float4 b, float acc) {
  acc = fmaf(a.x, b.x, acc);
  acc = fmaf(a.y, b.y, acc);
  acc = fmaf(a.z, b.z, acc);
  acc = fmaf(a.w, b.w, acc);
  return acc;
}

// ---------------------------------------------------------------------------
// Fused GRU over walks. Block = 512 threads = 8 waves, 32 walks.
// lane = tid&63: walk w = lane&31, j-octet jb = wave*16 + (lane>>5)*8.
// Each lane owns h[w][jb..jb+7] across all 20 steps (in registers),
// mirrored into LDS so every lane can read the full h-vector of its walk.
// ---------------------------------------------------------------------------
__global__ __launch_bounds__(512, 4)
void gru_kernel(const float* __restrict__ x, const int* __restrict__ walks,
                const float* __restrict__ W_c, const float* __restrict__ b_c,
                const float* __restrict__ W_hh, const float* __restrict__ b_hh,
                float* __restrict__ out) {
  __shared__ float xs[WPB][XSTR];
  __shared__ float hs[WPB][XSTR];
  __shared__ int   nodes[TLEN][WPB];

  const int tid  = threadIdx.x;
  const int lane = tid & 63;
  const int wv   = tid >> 6;                 // 0..7
  const int w    = lane & 31;                // walk within block
  const int jb   = wv * 16 + (lane >> 5) * 8;  // base hidden index (octet)
  const int walk0 = blockIdx.x * WPB;

  // preload walk node indices for this block
  for (int idx = tid; idx < TLEN * WPB; idx += 512) {
    const int t  = idx >> 5;
    const int ww = idx & 31;
    nodes[t][ww] = walks[(walk0 + ww) * TLEN + t];
  }
  // zero h in LDS
  for (int idx = tid; idx < WPB * HDIM; idx += 512)
    hs[idx >> 7][idx & 127] = 0.f;

  float hreg[8];
  #pragma unroll
  for (int jj = 0; jj < 8; ++jj) hreg[jj] = 0.f;

  const int srow = tid >> 4;    // 32 rows, 16 threads per row
  const int sc4  = tid & 15;    // float4 index within row

  __syncthreads();   // nodes + hs init visible

  #pragma unroll 1
  for (int t = 0; t < TLEN; ++t) {
    // ---- stage gathered x row into LDS (coalesced 256B segments) ----
    {
      const int node = nodes[t][srow];
      const float4* src = reinterpret_cast<const float4*>(x + (size_t)node * HDIM);
      const float4 a = src[sc4];
      const float4 b = src[sc4 + 16];
      *reinterpret_cast<float4*>(&xs[srow][sc4 * 4])      = a;
      *reinterpret_cast<float4*>(&xs[srow][sc4 * 4 + 64]) = b;
    }
    __syncthreads();

    // ---- accumulators (r,z fused over [x;h]; n needs xn/hn separate) ----
    float rs[8], zs[8], xn[8], hn[8];
    #pragma unroll
    for (int jj = 0; jj < 8; ++jj) {
      rs[jj] = b_c[jb + jj]            + b_hh[jb + jj];
      zs[jj] = b_c[HDIM + jb + jj]     + b_hh[HDIM + jb + jj];
      xn[jj] = b_c[2 * HDIM + jb + jj];
      hn[jj] = b_hh[2 * HDIM + jb + jj];
    }

    // ---- k-sweep: 6 dot products of length 128 per (w, j) ----
    #pragma unroll 1
    for (int kq = 0; kq < HDIM; kq += 4) {
      const float4 x4 = *reinterpret_cast<const float4*>(&xs[w][kq]);
      const float4 h4 = *reinterpret_cast<const float4*>(&hs[w][kq]);
      #pragma unroll
      for (int jj = 0; jj < 8; ++jj) {
        const int j = jb + jj;
        const float4 wxr = *reinterpret_cast<const float4*>(&W_c [(j)             * HDIM + kq]);
        const float4 wxz = *reinterpret_cast<const float4*>(&W_c [(j + HDIM)      * HDIM + kq]);
        const float4 wxn = *reinterpret_cast<const float4*>(&W_c [(j + 2 * HDIM)  * HDIM + kq]);
        const float4 whr = *reinterpret_cast<const float4*>(&W_hh[(j)             * HDIM + kq]);
        const float4 whz = *reinterpret_cast<const float4*>(&W_hh[(j + HDIM)      * HDIM + kq]);
        const float4 whn = *reinterpret_cast<const float4*>(&W_hh[(j + 2 * HDIM)  * HDIM + kq]);
        rs[jj] = dot4(h4, whr, dot4(x4, wxr, rs[jj]));
        zs[jj] = dot4(h4, whz, dot4(x4, wxz, zs[jj]));
        xn[jj] = dot4(x4, wxn, xn[jj]);
        hn[jj] = dot4(h4, whn, hn[jj]);
      }
    }

    // ---- gates ----
    #pragma unroll
    for (int jj = 0; jj < 8; ++jj) {
      float ra = fminf(fmaxf(rs[jj], -30.f), 30.f);
      float za = fminf(fmaxf(zs[jj], -30.f), 30.f);
      const float rg = 1.f / (1.f + __expf(-ra));
      const float zg = 1.f / (1.f + __expf(-za));
      float nv = xn[jj] + rg * hn[jj];
      nv = fminf(fmaxf(nv, -15.f), 15.f);
      const float e2 = __expf(2.f * nv);
      const float ng = (e2 - 1.f) / (e2 + 1.f);
      hreg[jj] = (1.f - zg) * ng + zg * hreg[jj];
    }

    __syncthreads();   // all k-sweep reads of hs/xs done before overwrite

    *reinterpret_cast<float4*>(&hs[w][jb])     = make_float4(hreg[0], hreg[1], hreg[2], hreg[3]);
    *reinterpret_cast<float4*>(&hs[w][jb + 4]) = make_float4(hreg[4], hreg[5], hreg[6], hreg[7]);
  }

  // ---- final output: h after last step ----
  float* dst = out + (size_t)(walk0 + w) * HDIM + jb;
  *reinterpret_cast<float4*>(dst)     = make_float4(hreg[0], hreg[1], hreg[2], hreg[3]);
  *reinterpret_cast<float4*>(dst + 4) = make_float4(hreg[4], hreg[5], hreg[6], hreg[7]);
}

extern "C" void kernel_launch(void* const* d_in, const int* in_sizes, int n_in,
                              void* d_out, int out_size, void* d_ws, size_t ws_size,
                              hipStream_t stream) {
  const float* x     = (const float*)d_in[0];
  const int*   walks = (const int*)  d_in[1];
  const float* W_f   = (const float*)d_in[2];
  const float* b_f   = (const float*)d_in[3];
  const float* W_ih  = (const float*)d_in[4];
  const float* W_hh  = (const float*)d_in[5];
  const float* b_ih  = (const float*)d_in[6];
  const float* b_hh  = (const float*)d_in[7];
  float* out = (float*)d_out;

  float* W_c = (float*)d_ws;            // 384*128 floats
  float* b_c = W_c + 384 * HDIM;        // 384 floats

  fold_kernel<<<3 * HDIM, HDIM, 0, stream>>>(W_f, b_f, W_ih, b_ih, W_c, b_c);
  gru_kernel<<<NWALKS / WPB, 512, 0, stream>>>(x, walks, W_c, b_c, W_hh, b_hh, out);
}

// Round 2
// 137.441 us; speedup vs baseline: 24.8409x; 24.8409x over previous
//
#include <hip/hip_runtime.h>
#include <cstddef>

#define NWALKS 16384
#define TLEN   20
#define HDIM   128
#define WPB    32     // walks per block (2 M-tiles of 16)
#define NTHR   512    // 8 waves
#define HSTR   136    // f16 LDS row stride (+8 pad -> 2-way max on frag reads)

typedef __attribute__((ext_vector_type(8))) _Float16 f16x8;
typedef __attribute__((ext_vector_type(4))) float    f32x4;

// ---------------------------------------------------------------------------
// fold: Wc16 = f16(W_ih @ W_f) [384x128], Whh16 = f16(W_hh), b_c = W_ih@b_f+b_ih
// ---------------------------------------------------------------------------
__global__ void fold_kernel(const float* __restrict__ W_f, const float* __restrict__ b_f,
                            const float* __restrict__ W_ih, const float* __restrict__ W_hh,
                            const float* __restrict__ b_ih,
                            _Float16* __restrict__ Wc16, _Float16* __restrict__ Whh16,
                            float* __restrict__ b_c) {
  const int r = blockIdx.x;    // 0..383
  const int i = threadIdx.x;   // 0..127
  const float* wih = W_ih + r * HDIM;
  float acc = 0.f;
  for (int h = 0; h < HDIM; ++h) acc = fmaf(wih[h], W_f[h * HDIM + i], acc);
  Wc16[r * HDIM + i]  = (_Float16)acc;
  Whh16[r * HDIM + i] = (_Float16)W_hh[r * HDIM + i];
  if (i == 0) {
    float bb = b_ih[r];
    for (int h = 0; h < HDIM; ++h) bb = fmaf(wih[h], b_f[h], bb);
    b_c[r] = bb;
  }
}

__device__ __forceinline__ float sigmoidf_(float v) {
  v = fminf(fmaxf(v, -30.f), 30.f);
  return 1.f / (1.f + __expf(-v));
}
__device__ __forceinline__ float tanhf_(float v) {
  v = fminf(fmaxf(v, -15.f), 15.f);
  const float e2 = __expf(2.f * v);
  return (e2 - 1.f) / (e2 + 1.f);
}

// ---------------------------------------------------------------------------
// Fused GRU, f16 MFMA. Wave wv owns gate columns [wv*16, wv*16+16) so the
// (r,z,xn,hn) quadruple for each (walk m, col j) lives in one lane -> gates
// are register-local. Weights persist in 96 VGPRs across all 20 steps.
// A-frag: lane reads in[m = mt*16 + (lane&15)][k = kt*32 + (lane>>4)*8 + 0..7]
// B-frag: lane reads W [n = wv*16 + (lane&15)][same k]          (C = A @ W^T)
// C/D   : m = mt*16 + (lane>>4)*4 + reg, n = wv*16 + (lane&15)  (m89-verified)
// ---------------------------------------------------------------------------
__global__ __launch_bounds__(NTHR, 2)
void gru_kernel(const float* __restrict__ x, const int* __restrict__ walks,
                const _Float16* __restrict__ Wc16, const _Float16* __restrict__ Whh16,
                const float* __restrict__ b_c, const float* __restrict__ b_hh,
                float* __restrict__ out) {
  __shared__ _Float16 hbuf[2][WPB][HSTR];
  __shared__ _Float16 xbuf[2][WPB][HSTR];
  __shared__ int      nodes[TLEN][WPB];

  const int tid  = threadIdx.x;
  const int lane = tid & 63;
  const int wv   = tid >> 6;        // 0..7 : gate-column group
  const int g    = lane >> 4;       // 0..3 : k-chunk / row-group
  const int l15  = lane & 15;
  const int j    = wv * 16 + l15;   // gate column 0..127
  const int walk0 = blockIdx.x * WPB;

  // preload walk node indices
  for (int idx = tid; idx < TLEN * WPB; idx += NTHR)
    nodes[idx >> 5][idx & 31] = walks[(walk0 + (idx & 31)) * TLEN + (idx >> 5)];
  // h_0 = 0
  for (int idx = tid; idx < WPB * HDIM; idx += NTHR)
    hbuf[0][idx >> 7][idx & 127] = (_Float16)0.f;

  // ---- persistent weight fragments (one-time load, 96 VGPR) ----
  f16x8 wrx[4], wrh[4], wzx[4], wzh[4], wnx[4], wnh[4];
#pragma unroll
  for (int kt = 0; kt < 4; ++kt) {
    const int koff = kt * 32 + g * 8;
    wrx[kt] = *(const f16x8*)(Wc16  + (size_t)(j)       * HDIM + koff);
    wzx[kt] = *(const f16x8*)(Wc16  + (size_t)(128 + j) * HDIM + koff);
    wnx[kt] = *(const f16x8*)(Wc16  + (size_t)(256 + j) * HDIM + koff);
    wrh[kt] = *(const f16x8*)(Whh16 + (size_t)(j)       * HDIM + koff);
    wzh[kt] = *(const f16x8*)(Whh16 + (size_t)(128 + j) * HDIM + koff);
    wnh[kt] = *(const f16x8*)(Whh16 + (size_t)(256 + j) * HDIM + koff);
  }
  const float br  = b_c[j]       + b_hh[j];
  const float bz  = b_c[128 + j] + b_hh[128 + j];
  const float bxn = b_c[256 + j];
  const float bhn = b_hh[256 + j];

  float hprev[2][4];
#pragma unroll
  for (int mt = 0; mt < 2; ++mt)
#pragma unroll
    for (int r = 0; r < 4; ++r) hprev[mt][r] = 0.f;

  // x staging: thread -> (row srow, 8-float chunk sc)
  const int srow = tid >> 4;
  const int sc   = tid & 15;

  __syncthreads();   // nodes visible

  { // stage x_0 (fp32 gather -> f16 LDS)
    const int node = nodes[0][srow];
    const float* src = x + (size_t)node * HDIM + sc * 8;
    const float4 a = *(const float4*)src;
    const float4 b = *(const float4*)(src + 4);
    f16x8 v;
    v[0]=(_Float16)a.x; v[1]=(_Float16)a.y; v[2]=(_Float16)a.z; v[3]=(_Float16)a.w;
    v[4]=(_Float16)b.x; v[5]=(_Float16)b.y; v[6]=(_Float16)b.z; v[7]=(_Float16)b.w;
    *(f16x8*)&xbuf[0][srow][sc * 8] = v;
  }
  __syncthreads();   // xbuf[0] + hbuf[0] visible

  const f32x4 zero4 = {0.f, 0.f, 0.f, 0.f};
  int cur = 0;

#pragma unroll 1
  for (int t = 0; t < TLEN; ++t) {
    // ---- prefetch x_{t+1}: issue gathered loads now, consume after MFMAs ----
    float4 pa, pb;
    const bool have = (t + 1 < TLEN);
    if (have) {
      const int node = nodes[t + 1][srow];
      const float* src = x + (size_t)node * HDIM + sc * 8;
      pa = *(const float4*)src;
      pb = *(const float4*)(src + 4);
    }

    f32x4 ar[2], az[2], an[2], ah2[2];
#pragma unroll
    for (int mt = 0; mt < 2; ++mt) { ar[mt]=zero4; az[mt]=zero4; an[mt]=zero4; ah2[mt]=zero4; }

#pragma unroll
    for (int kt = 0; kt < 4; ++kt) {
      const int koff = kt * 32 + g * 8;
      f16x8 ax0 = *(const f16x8*)&xbuf[cur][l15][koff];
      f16x8 ax1 = *(const f16x8*)&xbuf[cur][16 + l15][koff];
      f16x8 ah0 = *(const f16x8*)&hbuf[cur][l15][koff];
      f16x8 ah1 = *(const f16x8*)&hbuf[cur][16 + l15][koff];
      ar[0]  = __builtin_amdgcn_mfma_f32_16x16x32_f16(ax0, wrx[kt], ar[0],  0,0,0);
      ar[1]  = __builtin_amdgcn_mfma_f32_16x16x32_f16(ax1, wrx[kt], ar[1],  0,0,0);
      ar[0]  = __builtin_amdgcn_mfma_f32_16x16x32_f16(ah0, wrh[kt], ar[0],  0,0,0);
      ar[1]  = __builtin_amdgcn_mfma_f32_16x16x32_f16(ah1, wrh[kt], ar[1],  0,0,0);
      az[0]  = __builtin_amdgcn_mfma_f32_16x16x32_f16(ax0, wzx[kt], az[0],  0,0,0);
      az[1]  = __builtin_amdgcn_mfma_f32_16x16x32_f16(ax1, wzx[kt], az[1],  0,0,0);
      az[0]  = __builtin_amdgcn_mfma_f32_16x16x32_f16(ah0, wzh[kt], az[0],  0,0,0);
      az[1]  = __builtin_amdgcn_mfma_f32_16x16x32_f16(ah1, wzh[kt], az[1],  0,0,0);
      an[0]  = __builtin_amdgcn_mfma_f32_16x16x32_f16(ax0, wnx[kt], an[0],  0,0,0);
      an[1]  = __builtin_amdgcn_mfma_f32_16x16x32_f16(ax1, wnx[kt], an[1],  0,0,0);
      ah2[0] = __builtin_amdgcn_mfma_f32_16x16x32_f16(ah0, wnh[kt], ah2[0], 0,0,0);
      ah2[1] = __builtin_amdgcn_mfma_f32_16x16x32_f16(ah1, wnh[kt], ah2[1], 0,0,0);
    }

    // ---- write prefetched x_{t+1} into the other buffer ----
    if (have) {
      f16x8 v;
      v[0]=(_Float16)pa.x; v[1]=(_Float16)pa.y; v[2]=(_Float16)pa.z; v[3]=(_Float16)pa.w;
      v[4]=(_Float16)pb.x; v[5]=(_Float16)pb.y; v[6]=(_Float16)pb.z; v[7]=(_Float16)pb.w;
      *(f16x8*)&xbuf[cur ^ 1][srow][sc * 8] = v;
    }

    // ---- gates: fully lane-local (r,z,xn,hn all at same (lane, reg)) ----
#pragma unroll
    for (int mt = 0; mt < 2; ++mt)
#pragma unroll
      for (int r = 0; r < 4; ++r) {
        const float rv   = sigmoidf_(ar[mt][r] + br);
        const float zv   = sigmoidf_(az[mt][r] + bz);
        const float nv   = tanhf_((an[mt][r] + bxn) + rv * (ah2[mt][r] + bhn));
        const float hnew = (1.f - zv) * nv + zv * hprev[mt][r];
        hprev[mt][r] = hnew;
        hbuf[cur ^ 1][mt * 16 + 4 * g + r][j] = (_Float16)hnew;
      }

    __syncthreads();   // h_{t}/x_{t+1} visible; old buffers free for reuse
    cur ^= 1;
  }

  // ---- final h (kept in fp32 registers, no f16 round-trip) ----
#pragma unroll
  for (int mt = 0; mt < 2; ++mt)
#pragma unroll
    for (int r = 0; r < 4; ++r)
      out[(size_t)(walk0 + mt * 16 + 4 * g + r) * HDIM + j] = hprev[mt][r];
}

extern "C" void kernel_launch(void* const* d_in, const int* in_sizes, int n_in,
                              void* d_out, int out_size, void* d_ws, size_t ws_size,
                              hipStream_t stream) {
  const float* x     = (const float*)d_in[0];
  const int*   walks = (const int*)  d_in[1];
  const float* W_f   = (const float*)d_in[2];
  const float* b_f   = (const float*)d_in[3];
  const float* W_ih  = (const float*)d_in[4];
  const float* W_hh  = (const float*)d_in[5];
  const float* b_ih  = (const float*)d_in[6];
  const float* b_hh  = (const float*)d_in[7];
  float* out = (float*)d_out;

  _Float16* Wc16  = (_Float16*)d_ws;                 // 384*128 f16 = 96 KiB
  _Float16* Whh16 = Wc16 + 384 * HDIM;               // 384*128 f16 = 96 KiB
  float*    b_c   = (float*)(Whh16 + 384 * HDIM);    // 384 f32

  fold_kernel<<<3 * HDIM, HDIM, 0, stream>>>(W_f, b_f, W_ih, W_hh, b_ih, Wc16, Whh16, b_c);
  gru_kernel<<<NWALKS / WPB, NTHR, 0, stream>>>(x, walks, Wc16, Whh16, b_c, b_hh, out);
}

// Round 4
// 85.236 us; speedup vs baseline: 40.0555x; 1.6125x over previous
//
#include <hip/hip_runtime.h>
#include <cstddef>

#define NWALKS 16384
#define TLEN   20
#define HDIM   128
#define WPB    32     // walks per block (2 tiles of 16 columns)
#define NTHR   512    // 8 waves
#define HSTR   136    // f16 LDS row stride (+8 pad -> <=2-way bank aliasing)

typedef __attribute__((ext_vector_type(8))) _Float16 f16x8;
typedef __attribute__((ext_vector_type(4))) _Float16 f16x4;
typedef __attribute__((ext_vector_type(2))) __fp16   h16x2;   // cvt_pkrtz result type
typedef __attribute__((ext_vector_type(4))) float    f32x4;

union H4 { f16x4 v; struct { h16x2 lo, hi; } p; };

// ---------------------------------------------------------------------------
// fold: Wc16 = f16(W_ih @ W_f) [384x128], Whh16 = f16(W_hh), b_c = W_ih@b_f+b_ih
// ---------------------------------------------------------------------------
__global__ void fold_kernel(const float* __restrict__ W_f, const float* __restrict__ b_f,
                            const float* __restrict__ W_ih, const float* __restrict__ W_hh,
                            const float* __restrict__ b_ih,
                            _Float16* __restrict__ Wc16, _Float16* __restrict__ Whh16,
                            float* __restrict__ b_c) {
  const int r = blockIdx.x;    // 0..383
  const int i = threadIdx.x;   // 0..127
  const float* wih = W_ih + r * HDIM;
  float acc = 0.f;
  for (int h = 0; h < HDIM; ++h) acc = fmaf(wih[h], W_f[h * HDIM + i], acc);
  Wc16[r * HDIM + i]  = (_Float16)acc;
  Whh16[r * HDIM + i] = (_Float16)W_hh[r * HDIM + i];
  if (i == 0) {
    float bb = b_ih[r];
    for (int h = 0; h < HDIM; ++h) bb = fmaf(wih[h], b_f[h], bb);
    b_c[r] = bb;
  }
}

__device__ __forceinline__ float fsig(float v) {
  // 1/(1+e^-v), inf-safe: v->-inf: rcp(inf)=0 ; v->+inf: rcp(1)=1
  return __builtin_amdgcn_rcpf(1.f + __builtin_amdgcn_exp2f(-1.4426950408889634f * v));
}
__device__ __forceinline__ float ftanh(float v) {
  // 1 - 2/(e^{2v}+1), inf-safe: v->+inf: 1 ; v->-inf: -1
  const float e2 = __builtin_amdgcn_exp2f(2.8853900817779268f * v);
  return fmaf(-2.f, __builtin_amdgcn_rcpf(e2 + 1.f), 1.f);
}

// ---------------------------------------------------------------------------
// Fused GRU, f16 MFMA, D = W_frag(A) x in_frag(B) -> rows = j, cols = walk.
// Lane (g = lane>>4, l15 = lane&15) holds gates for j = wv*16+4g+{0..3},
// walk = mt*16 + l15. Weights persist in 96 regs; biases fold into acc init.
// Pipeline: step t issues gather for x[t+2] (regs), writes x[t+1] to LDS
// after the MFMAs, computes gates, one barrier. Double-buffered x/h in LDS.
// ---------------------------------------------------------------------------
__global__ __launch_bounds__(NTHR, 2)
void gru_kernel(const float* __restrict__ x, const int* __restrict__ walks,
                const _Float16* __restrict__ Wc16, const _Float16* __restrict__ Whh16,
                const float* __restrict__ b_c, const float* __restrict__ b_hh,
                float* __restrict__ out) {
  __shared__ _Float16 hbuf[2][WPB][HSTR];
  __shared__ _Float16 xbuf[2][WPB][HSTR];
  __shared__ int      nodes[TLEN][WPB];

  const int tid  = threadIdx.x;
  const int lane = tid & 63;
  const int wv   = tid >> 6;        // 0..7 : j-tile
  const int g    = lane >> 4;       // 0..3 : k-chunk / j-quad
  const int l15  = lane & 15;
  const int jw   = wv * 16 + l15;   // weight row for frag loads
  const int j0   = wv * 16 + 4 * g; // this lane's 4 j-columns
  const int walk0 = blockIdx.x * WPB;

  for (int idx = tid; idx < TLEN * WPB; idx += NTHR)
    nodes[idx >> 5][idx & 31] = walks[(walk0 + (idx & 31)) * TLEN + (idx >> 5)];
  for (int idx = tid; idx < WPB * HDIM; idx += NTHR)
    hbuf[0][idx >> 7][idx & 127] = (_Float16)0.f;

  // ---- persistent weight fragments (A-operand), 96 VGPR ----
  f16x8 wrx[4], wrh[4], wzx[4], wzh[4], wnx[4], wnh[4];
#pragma unroll
  for (int kt = 0; kt < 4; ++kt) {
    const int koff = kt * 32 + g * 8;
    wrx[kt] = *(const f16x8*)(Wc16  + (size_t)(jw)       * HDIM + koff);
    wzx[kt] = *(const f16x8*)(Wc16  + (size_t)(128 + jw) * HDIM + koff);
    wnx[kt] = *(const f16x8*)(Wc16  + (size_t)(256 + jw) * HDIM + koff);
    wrh[kt] = *(const f16x8*)(Whh16 + (size_t)(jw)       * HDIM + koff);
    wzh[kt] = *(const f16x8*)(Whh16 + (size_t)(128 + jw) * HDIM + koff);
    wnh[kt] = *(const f16x8*)(Whh16 + (size_t)(256 + jw) * HDIM + koff);
  }
  // ---- biases as float4 over the lane's j-quad ----
  const f32x4 br4  = *(const f32x4*)&b_c[j0]        + *(const f32x4*)&b_hh[j0];
  const f32x4 bz4  = *(const f32x4*)&b_c[128 + j0]  + *(const f32x4*)&b_hh[128 + j0];
  const f32x4 bxn4 = *(const f32x4*)&b_c[256 + j0];
  const f32x4 bhn4 = *(const f32x4*)&b_hh[256 + j0];

  f32x4 hprev[2];
  hprev[0] = 0.f; hprev[1] = 0.f;

  // x staging: 32 rows, 16 threads/row, 8 floats each
  const int srow = tid >> 4;
  const int sc   = tid & 15;

  __syncthreads();   // nodes visible

  // ---- prologue: stage x[0] into xbuf[0]; load x[1] into regs ----
  {
    const unsigned off0 = ((unsigned)nodes[0][srow] << 7) + sc * 8u;
    const f32x4 a = *(const f32x4*)(x + off0);
    const f32x4 b = *(const f32x4*)(x + off0 + 4);
    H4 lo, hi;
    lo.p.lo = __builtin_amdgcn_cvt_pkrtz(a.x, a.y);
    lo.p.hi = __builtin_amdgcn_cvt_pkrtz(a.z, a.w);
    hi.p.lo = __builtin_amdgcn_cvt_pkrtz(b.x, b.y);
    hi.p.hi = __builtin_amdgcn_cvt_pkrtz(b.z, b.w);
    *(f16x4*)&xbuf[0][srow][sc * 8]     = lo.v;
    *(f16x4*)&xbuf[0][srow][sc * 8 + 4] = hi.v;
  }
  f32x4 PA0, PA1, PB0, PB1;
  {
    const unsigned off1 = ((unsigned)nodes[1][srow] << 7) + sc * 8u;
    PA0 = *(const f32x4*)(x + off1);
    PA1 = *(const f32x4*)(x + off1 + 4);
  }
  __syncthreads();   // xbuf[0] + hbuf[0] visible

#define STEP(T, CUR, NXT, P0, P1, N0, N1)                                         \
  {                                                                               \
    /* 1. issue gather for x[T+2] (consumed next step) */                         \
    const int tn = ((T) + 2 < TLEN) ? (T) + 2 : TLEN - 1;                         \
    const unsigned offn = ((unsigned)nodes[tn][srow] << 7) + sc * 8u;             \
    N0 = *(const f32x4*)(x + offn);                                               \
    N1 = *(const f32x4*)(x + offn + 4);                                           \
    /* 2. activation fragments (B-operand) */                                     \
    f32x4 ar[2], az[2], an[2], ah2[2];                                            \
    ar[0] = br4;  ar[1] = br4;  az[0] = bz4;  az[1] = bz4;                        \
    an[0] = bxn4; an[1] = bxn4; ah2[0] = bhn4; ah2[1] = bhn4;                     \
    _Pragma("unroll")                                                             \
    for (int kt = 0; kt < 4; ++kt) {                                              \
      const int koff = kt * 32 + g * 8;                                           \
      const f16x8 ax0 = *(const f16x8*)&xbuf[CUR][l15][koff];                     \
      const f16x8 ax1 = *(const f16x8*)&xbuf[CUR][16 + l15][koff];                \
      const f16x8 ah0 = *(const f16x8*)&hbuf[CUR][l15][koff];                     \
      const f16x8 ah1 = *(const f16x8*)&hbuf[CUR][16 + l15][koff];                \
      ar[0]  = __builtin_amdgcn_mfma_f32_16x16x32_f16(wrx[kt], ax0, ar[0],  0,0,0); \
      ar[1]  = __builtin_amdgcn_mfma_f32_16x16x32_f16(wrx[kt], ax1, ar[1],  0,0,0); \
      ar[0]  = __builtin_amdgcn_mfma_f32_16x16x32_f16(wrh[kt], ah0, ar[0],  0,0,0); \
      ar[1]  = __builtin_amdgcn_mfma_f32_16x16x32_f16(wrh[kt], ah1, ar[1],  0,0,0); \
      az[0]  = __builtin_amdgcn_mfma_f32_16x16x32_f16(wzx[kt], ax0, az[0],  0,0,0); \
      az[1]  = __builtin_amdgcn_mfma_f32_16x16x32_f16(wzx[kt], ax1, az[1],  0,0,0); \
      az[0]  = __builtin_amdgcn_mfma_f32_16x16x32_f16(wzh[kt], ah0, az[0],  0,0,0); \
      az[1]  = __builtin_amdgcn_mfma_f32_16x16x32_f16(wzh[kt], ah1, az[1],  0,0,0); \
      an[0]  = __builtin_amdgcn_mfma_f32_16x16x32_f16(wnx[kt], ax0, an[0],  0,0,0); \
      an[1]  = __builtin_amdgcn_mfma_f32_16x16x32_f16(wnx[kt], ax1, an[1],  0,0,0); \
      ah2[0] = __builtin_amdgcn_mfma_f32_16x16x32_f16(wnh[kt], ah0, ah2[0], 0,0,0); \
      ah2[1] = __builtin_amdgcn_mfma_f32_16x16x32_f16(wnh[kt], ah1, ah2[1], 0,0,0); \
    }                                                                             \
    /* 3. write x[T+1] (loaded last step) into the other buffer */                \
    {                                                                             \
      H4 lo, hi;                                                                  \
      lo.p.lo = __builtin_amdgcn_cvt_pkrtz(P0.x, P0.y);                           \
      lo.p.hi = __builtin_amdgcn_cvt_pkrtz(P0.z, P0.w);                           \
      hi.p.lo = __builtin_amdgcn_cvt_pkrtz(P1.x, P1.y);                           \
      hi.p.hi = __builtin_amdgcn_cvt_pkrtz(P1.z, P1.w);                           \
      *(f16x4*)&xbuf[NXT][srow][sc * 8]     = lo.v;                               \
      *(f16x4*)&xbuf[NXT][srow][sc * 8 + 4] = hi.v;                               \
    }                                                                             \
    /* 4. gates (lane-local) + h writeback (b64) */                               \
    _Pragma("unroll")                                                             \
    for (int mt = 0; mt < 2; ++mt) {                                              \
      f32x4 hn;                                                                   \
      _Pragma("unroll")                                                           \
      for (int r = 0; r < 4; ++r) {                                               \
        const float rv = fsig(ar[mt][r]);                                         \
        const float zv = fsig(az[mt][r]);                                         \
        const float nv = ftanh(fmaf(rv, ah2[mt][r], an[mt][r]));                  \
        hn[r] = fmaf(zv, hprev[mt][r] - nv, nv);                                  \
      }                                                                           \
      hprev[mt] = hn;                                                             \
      H4 hp;                                                                      \
      hp.p.lo = __builtin_amdgcn_cvt_pkrtz(hn[0], hn[1]);                         \
      hp.p.hi = __builtin_amdgcn_cvt_pkrtz(hn[2], hn[3]);                         \
      *(f16x4*)&hbuf[NXT][mt * 16 + l15][j0] = hp.v;                              \
    }                                                                             \
    __syncthreads();                                                              \
  }

#pragma unroll 1
  for (int tt = 0; tt < TLEN; tt += 2) {
    STEP(tt,     0, 1, PA0, PA1, PB0, PB1)
    STEP(tt + 1, 1, 0, PB0, PB1, PA0, PA1)
  }
#undef STEP

  // ---- final h: lane holds j0..j0+3 for walks l15, 16+l15 ----
#pragma unroll
  for (int mt = 0; mt < 2; ++mt) {
    float4 o = make_float4(hprev[mt][0], hprev[mt][1], hprev[mt][2], hprev[mt][3]);
    *(float4*)&out[(size_t)(walk0 + mt * 16 + l15) * HDIM + j0] = o;
  }
}

extern "C" void kernel_launch(void* const* d_in, const int* in_sizes, int n_in,
                              void* d_out, int out_size, void* d_ws, size_t ws_size,
                              hipStream_t stream) {
  const float* x     = (const float*)d_in[0];
  const int*   walks = (const int*)  d_in[1];
  const float* W_f   = (const float*)d_in[2];
  const float* b_f   = (const float*)d_in[3];
  const float* W_ih  = (const float*)d_in[4];
  const float* W_hh  = (const float*)d_in[5];
  const float* b_ih  = (const float*)d_in[6];
  const float* b_hh  = (const float*)d_in[7];
  float* out = (float*)d_out;

  _Float16* Wc16  = (_Float16*)d_ws;                 // 384*128 f16
  _Float16* Whh16 = Wc16 + 384 * HDIM;               // 384*128 f16
  float*    b_c   = (float*)(Whh16 + 384 * HDIM);    // 384 f32

  fold_kernel<<<3 * HDIM, HDIM, 0, stream>>>(W_f, b_f, W_ih, W_hh, b_ih, Wc16, Whh16, b_c);
  gru_kernel<<<NWALKS / WPB, NTHR, 0, stream>>>(x, walks, Wc16, Whh16, b_c, b_hh, out);
}

// Round 5
// 83.870 us; speedup vs baseline: 40.7078x; 1.0163x over previous
//
#include <hip/hip_runtime.h>
#include <cstddef>

#define NWALKS 16384
#define TLEN   20
#define HDIM   128
#define WPB    32     // walks per block (2 tiles of 16 columns)
#define NTHR   512    // 8 waves

typedef __attribute__((ext_vector_type(8))) _Float16 f16x8;
typedef __attribute__((ext_vector_type(4))) _Float16 f16x4;
typedef __attribute__((ext_vector_type(2))) __fp16   h16x2;   // cvt_pkrtz result type
typedef __attribute__((ext_vector_type(4))) float    f32x4;

union H4 { f16x4 v; struct { h16x2 lo, hi; } p; };

// ---------------------------------------------------------------------------
// fold: Wc16 = f16(scale_row * (W_ih @ W_f)), Whh16 = f16(scale_row * W_hh),
// b_c = W_ih@b_f + b_ih (unscaled; scaled at load in gru_kernel).
// Row scaling folds the exp2 arguments into the weights:
//   r,z rows (0..255):  * -log2(e)   -> sigmoid(v) = rcp(1 + exp2(acc))
//   n  rows (256..383): * +2*log2(e) -> tanh(v)    = 1 - 2*rcp(exp2(acc)+1)
// ---------------------------------------------------------------------------
__global__ void fold_kernel(const float* __restrict__ W_f, const float* __restrict__ b_f,
                            const float* __restrict__ W_ih, const float* __restrict__ W_hh,
                            const float* __restrict__ b_ih,
                            _Float16* __restrict__ Wc16, _Float16* __restrict__ Whh16,
                            float* __restrict__ b_c) {
  const int r = blockIdx.x;    // 0..383
  const int i = threadIdx.x;   // 0..127
  const float scale = (r < 256) ? -1.4426950408889634f : 2.8853900817779268f;
  const float* wih = W_ih + r * HDIM;
  float acc = 0.f;
  for (int h = 0; h < HDIM; ++h) acc = fmaf(wih[h], W_f[h * HDIM + i], acc);
  Wc16[r * HDIM + i]  = (_Float16)(acc * scale);
  Whh16[r * HDIM + i] = (_Float16)(W_hh[r * HDIM + i] * scale);
  if (i == 0) {
    float bb = b_ih[r];
    for (int h = 0; h < HDIM; ++h) bb = fmaf(wih[h], b_f[h], bb);
    b_c[r] = bb;
  }
}

// ---------------------------------------------------------------------------
// Fused GRU, f16 MFMA. Wave wv owns gate columns [wv*16, wv*16+16); lane
// (g = lane>>4, l15 = lane&15) holds gates for j = wv*16+4g+{0..3},
// walk = mt*16 + l15. Weights persist in 96 regs; biases enter via MFMA C-in.
// LDS x/h tiles are XOR-swizzled on the 16B-chunk index (chunk ^= row&7) at
// every access site -> conflict-free ds_read_b128 / ds_write.
// Pipeline: step t issues gather for x[t+2] (regs), writes x[t+1] to LDS
// after the MFMAs, computes gates, one barrier. Double-buffered x/h in LDS.
// ---------------------------------------------------------------------------
__global__ __launch_bounds__(NTHR, 2)
void gru_kernel(const float* __restrict__ x, const int* __restrict__ walks,
                const _Float16* __restrict__ Wc16, const _Float16* __restrict__ Whh16,
                const float* __restrict__ b_c, const float* __restrict__ b_hh,
                float* __restrict__ out) {
  __shared__ _Float16 hbuf[2][WPB][HDIM];
  __shared__ _Float16 xbuf[2][WPB][HDIM];
  __shared__ int      nodes[TLEN][WPB];

  const int tid  = threadIdx.x;
  const int lane = tid & 63;
  const int wv   = tid >> 6;        // 0..7 : j-tile
  const int g    = lane >> 4;       // 0..3 : k-chunk / j-quad
  const int l15  = lane & 15;
  const int jw   = wv * 16 + l15;   // weight row for frag loads
  const int j0   = wv * 16 + 4 * g; // this lane's 4 j-columns
  const int walk0 = blockIdx.x * WPB;

  for (int idx = tid; idx < TLEN * WPB; idx += NTHR)
    nodes[idx >> 5][idx & 31] = walks[(walk0 + (idx & 31)) * TLEN + (idx >> 5)];
  for (int idx = tid; idx < WPB * HDIM; idx += NTHR)
    hbuf[0][0][idx] = (_Float16)0.f;   // zero fill: swizzle-invariant

  // ---- persistent weight fragments (A-operand), 96 VGPR ----
  f16x8 wrx[4], wrh[4], wzx[4], wzh[4], wnx[4], wnh[4];
#pragma unroll
  for (int kt = 0; kt < 4; ++kt) {
    const int koff = kt * 32 + g * 8;
    wrx[kt] = *(const f16x8*)(Wc16  + (size_t)(jw)       * HDIM + koff);
    wzx[kt] = *(const f16x8*)(Wc16  + (size_t)(128 + jw) * HDIM + koff);
    wnx[kt] = *(const f16x8*)(Wc16  + (size_t)(256 + jw) * HDIM + koff);
    wrh[kt] = *(const f16x8*)(Whh16 + (size_t)(jw)       * HDIM + koff);
    wzh[kt] = *(const f16x8*)(Whh16 + (size_t)(128 + jw) * HDIM + koff);
    wnh[kt] = *(const f16x8*)(Whh16 + (size_t)(256 + jw) * HDIM + koff);
  }
  // ---- biases (scaled to match weight row scaling), used as MFMA C-in ----
  const float NEG_L2E = -1.4426950408889634f;
  const float TWO_L2E =  2.8853900817779268f;
  const f32x4 br4  = NEG_L2E * (*(const f32x4*)&b_c[j0]       + *(const f32x4*)&b_hh[j0]);
  const f32x4 bz4  = NEG_L2E * (*(const f32x4*)&b_c[128 + j0] + *(const f32x4*)&b_hh[128 + j0]);
  const f32x4 bxn4 = TWO_L2E * (*(const f32x4*)&b_c[256 + j0]);
  const f32x4 bhn4 = TWO_L2E * (*(const f32x4*)&b_hh[256 + j0]);

  f32x4 hprev[2];
  hprev[0] = 0.f; hprev[1] = 0.f;

  // ---- swizzled LDS offsets (f16-element units), computed once ----
  // frag reads: row l15 (and +16 via +2048), chunk kt*4+g
  int voffs[4];
#pragma unroll
  for (int kt = 0; kt < 4; ++kt)
    voffs[kt] = l15 * HDIM + ((((kt * 4 + g) ^ (l15 & 7))) << 3);
  // x staging: 32 rows, 16 threads/row, chunk sc
  const int srow = tid >> 4;
  const int sc   = tid & 15;
  const int xw   = srow * HDIM + ((sc ^ (srow & 7)) << 3);
  // h write: row l15 (+2048 for mt=1), chunk 2wv+(g>>1), half (g&1)
  const int hw   = l15 * HDIM + (((2 * wv + (g >> 1)) ^ (l15 & 7)) << 3) + ((g & 1) << 2);

  __syncthreads();   // nodes visible

  // ---- prologue: stage x[0] into xbuf[0]; load x[1] into regs ----
  {
    const unsigned off0 = ((unsigned)nodes[0][srow] << 7) + sc * 8u;
    const f32x4 a = *(const f32x4*)(x + off0);
    const f32x4 b = *(const f32x4*)(x + off0 + 4);
    H4 lo, hi;
    lo.p.lo = __builtin_amdgcn_cvt_pkrtz(a.x, a.y);
    lo.p.hi = __builtin_amdgcn_cvt_pkrtz(a.z, a.w);
    hi.p.lo = __builtin_amdgcn_cvt_pkrtz(b.x, b.y);
    hi.p.hi = __builtin_amdgcn_cvt_pkrtz(b.z, b.w);
    *(f16x4*)(&xbuf[0][0][0] + xw)     = lo.v;
    *(f16x4*)(&xbuf[0][0][0] + xw + 4) = hi.v;
  }
  f32x4 PA0, PA1, PB0, PB1;
  {
    const unsigned off1 = ((unsigned)nodes[1][srow] << 7) + sc * 8u;
    PA0 = *(const f32x4*)(x + off1);
    PA1 = *(const f32x4*)(x + off1 + 4);
  }
  __syncthreads();   // xbuf[0] + hbuf[0] visible

#define STEP(T, CUR, NXT, P0, P1, N0, N1)                                         \
  {                                                                               \
    /* 1. issue gather for x[T+2] (consumed next step) */                         \
    const int tn = ((T) + 2 < TLEN) ? (T) + 2 : TLEN - 1;                         \
    const unsigned offn = ((unsigned)nodes[tn][srow] << 7) + sc * 8u;             \
    N0 = *(const f32x4*)(x + offn);                                               \
    N1 = *(const f32x4*)(x + offn + 4);                                           \
    /* 2. MFMAs; bias enters as C-in on kt==0 */                                  \
    const _Float16* xb = &xbuf[CUR][0][0];                                        \
    const _Float16* hb = &hbuf[CUR][0][0];                                        \
    f32x4 ar[2], az[2], an[2], ah2[2];                                            \
    __builtin_amdgcn_s_setprio(1);                                                \
    _Pragma("unroll")                                                             \
    for (int kt = 0; kt < 4; ++kt) {                                              \
      const f16x8 ax0 = *(const f16x8*)(xb + voffs[kt]);                          \
      const f16x8 ax1 = *(const f16x8*)(xb + voffs[kt] + 16 * HDIM);              \
      const f16x8 ah0 = *(const f16x8*)(hb + voffs[kt]);                          \
      const f16x8 ah1 = *(const f16x8*)(hb + voffs[kt] + 16 * HDIM);              \
      ar[0]  = __builtin_amdgcn_mfma_f32_16x16x32_f16(wrx[kt], ax0, kt ? ar[0]  : br4,  0,0,0); \
      ar[1]  = __builtin_amdgcn_mfma_f32_16x16x32_f16(wrx[kt], ax1, kt ? ar[1]  : br4,  0,0,0); \
      ar[0]  = __builtin_amdgcn_mfma_f32_16x16x32_f16(wrh[kt], ah0, ar[0],  0,0,0); \
      ar[1]  = __builtin_amdgcn_mfma_f32_16x16x32_f16(wrh[kt], ah1, ar[1],  0,0,0); \
      az[0]  = __builtin_amdgcn_mfma_f32_16x16x32_f16(wzx[kt], ax0, kt ? az[0]  : bz4,  0,0,0); \
      az[1]  = __builtin_amdgcn_mfma_f32_16x16x32_f16(wzx[kt], ax1, kt ? az[1]  : bz4,  0,0,0); \
      az[0]  = __builtin_amdgcn_mfma_f32_16x16x32_f16(wzh[kt], ah0, az[0],  0,0,0); \
      az[1]  = __builtin_amdgcn_mfma_f32_16x16x32_f16(wzh[kt], ah1, az[1],  0,0,0); \
      an[0]  = __builtin_amdgcn_mfma_f32_16x16x32_f16(wnx[kt], ax0, kt ? an[0]  : bxn4, 0,0,0); \
      an[1]  = __builtin_amdgcn_mfma_f32_16x16x32_f16(wnx[kt], ax1, kt ? an[1]  : bxn4, 0,0,0); \
      ah2[0] = __builtin_amdgcn_mfma_f32_16x16x32_f16(wnh[kt], ah0, kt ? ah2[0] : bhn4, 0,0,0); \
      ah2[1] = __builtin_amdgcn_mfma_f32_16x16x32_f16(wnh[kt], ah1, kt ? ah2[1] : bhn4, 0,0,0); \
    }                                                                             \
    __builtin_amdgcn_s_setprio(0);                                                \
    /* 3. write x[T+1] (loaded last step) into the other buffer */                \
    {                                                                             \
      H4 lo, hi;                                                                  \
      lo.p.lo = __builtin_amdgcn_cvt_pkrtz(P0.x, P0.y);                           \
      lo.p.hi = __builtin_amdgcn_cvt_pkrtz(P0.z, P0.w);                           \
      hi.p.lo = __builtin_amdgcn_cvt_pkrtz(P1.x, P1.y);                           \
      hi.p.hi = __builtin_amdgcn_cvt_pkrtz(P1.z, P1.w);                           \
      *(f16x4*)(&xbuf[NXT][0][0] + xw)     = lo.v;                                \
      *(f16x4*)(&xbuf[NXT][0][0] + xw + 4) = hi.v;                                \
    }                                                                             \
    /* 4. gates (lane-local, scaled-exp2 forms) + h writeback (b64) */            \
    _Pragma("unroll")                                                             \
    for (int mt = 0; mt < 2; ++mt) {                                              \
      f32x4 hn;                                                                   \
      _Pragma("unroll")                                                           \
      for (int r = 0; r < 4; ++r) {                                               \
        const float rv = __builtin_amdgcn_rcpf(1.f + __builtin_amdgcn_exp2f(ar[mt][r])); \
        const float zv = __builtin_amdgcn_rcpf(1.f + __builtin_amdgcn_exp2f(az[mt][r])); \
        const float en = __builtin_amdgcn_exp2f(fmaf(rv, ah2[mt][r], an[mt][r])); \
        const float nv = fmaf(-2.f, __builtin_amdgcn_rcpf(en + 1.f), 1.f);        \
        hn[r] = fmaf(zv, hprev[mt][r] - nv, nv);                                  \
      }                                                                           \
      hprev[mt] = hn;                                                             \
      H4 hp;                                                                      \
      hp.p.lo = __builtin_amdgcn_cvt_pkrtz(hn[0], hn[1]);                         \
      hp.p.hi = __builtin_amdgcn_cvt_pkrtz(hn[2], hn[3]);                         \
      *(f16x4*)(&hbuf[NXT][0][0] + hw + mt * 16 * HDIM) = hp.v;                   \
    }                                                                             \
    __syncthreads();                                                              \
  }

#pragma unroll 1
  for (int tt = 0; tt < TLEN; tt += 2) {
    STEP(tt,     0, 1, PA0, PA1, PB0, PB1)
    STEP(tt + 1, 1, 0, PB0, PB1, PA0, PA1)
  }
#undef STEP

  // ---- final h: lane holds j0..j0+3 for walks l15, 16+l15 ----
#pragma unroll
  for (int mt = 0; mt < 2; ++mt) {
    float4 o = make_float4(hprev[mt][0], hprev[mt][1], hprev[mt][2], hprev[mt][3]);
    *(float4*)&out[(size_t)(walk0 + mt * 16 + l15) * HDIM + j0] = o;
  }
}

extern "C" void kernel_launch(void* const* d_in, const int* in_sizes, int n_in,
                              void* d_out, int out_size, void* d_ws, size_t ws_size,
                              hipStream_t stream) {
  const float* x     = (const float*)d_in[0];
  const int*   walks = (const int*)  d_in[1];
  const float* W_f   = (const float*)d_in[2];
  const float* b_f   = (const float*)d_in[3];
  const float* W_ih  = (const float*)d_in[4];
  const float* W_hh  = (const float*)d_in[5];
  const float* b_ih  = (const float*)d_in[6];
  const float* b_hh  = (const float*)d_in[7];
  float* out = (float*)d_out;

  _Float16* Wc16  = (_Float16*)d_ws;                 // 384*128 f16
  _Float16* Whh16 = Wc16 + 384 * HDIM;               // 384*128 f16
  float*    b_c   = (float*)(Whh16 + 384 * HDIM);    // 384 f32

  fold_kernel<<<3 * HDIM, HDIM, 0, stream>>>(W_f, b_f, W_ih, W_hh, b_ih, Wc16, Whh16, b_c);
  gru_kernel<<<NWALKS / WPB, NTHR, 0, stream>>>(x, walks, Wc16, Whh16, b_c, b_hh, out);
}